// Round 1
// 1615.444 us; speedup vs baseline: 1.1107x; 1.1107x over previous
//
#include <hip/hip_runtime.h>
#include <math.h>

#define L_ 2
#define D_ 1024
#define H_ 16
#define HD_ 64
#define DFF_ 4096
#define V_ 32000
#define B_ 2
#define S_ 1024
#define BS_ (B_*S_)
#define D3_ (3*D_)
#define VC_ 6400   // vocab chunk: 50 tiles of 128

typedef __attribute__((ext_vector_type(8))) short short8;
typedef __attribute__((ext_vector_type(4))) float f32x4;
typedef __attribute__((ext_vector_type(4))) unsigned int uint4v;

__device__ __forceinline__ float b2f(unsigned short u) {
    return __uint_as_float(((unsigned int)u) << 16);
}
__device__ __forceinline__ unsigned short f2b(float f) {
    unsigned int u = __float_as_uint(f);
    return (unsigned short)((u + 0x7fffu + ((u >> 16) & 1u)) >> 16);
}
__device__ __forceinline__ float blo(unsigned int u) { return __uint_as_float(u << 16); }
__device__ __forceinline__ float bhi(unsigned int u) { return __uint_as_float(u & 0xffff0000u); }

__device__ __forceinline__ void gld16(const void* g, void* l) {
    __builtin_amdgcn_global_load_lds(
        (const __attribute__((address_space(1))) unsigned int*)g,
        (__attribute__((address_space(3))) unsigned int*)l, 16, 0, 0);
}

// ---------------- merges ----------------

// fp32 merge (small gammas): out[i] = base[i] + l0*d[i] + l1*d[i+tstride]
__global__ void merge_f32_kernel(const float* __restrict__ base, const float* __restrict__ dlt,
                                 size_t tstride, const float* __restrict__ lam,
                                 float* __restrict__ out, int n) {
    float l0 = lam[0], l1 = lam[1];
    for (int i = blockIdx.x * blockDim.x + threadIdx.x; i < n; i += gridDim.x * blockDim.x)
        out[i] = base[i] + l0 * dlt[i] + l1 * dlt[i + tstride];
}

// fp32 -> bf16 merge, no transpose (embedding). n4 = count of float4 groups.
__global__ void merge_bf16_kernel(const float* __restrict__ base, const float* __restrict__ dlt,
                                  size_t tstride, const float* __restrict__ lam,
                                  unsigned short* __restrict__ out, size_t n4) {
    float l0 = lam[0], l1 = lam[1];
    for (size_t q = blockIdx.x * blockDim.x + threadIdx.x; q < n4; q += (size_t)gridDim.x * blockDim.x) {
        size_t i = q * 4;
        float4 b = *(const float4*)(base + i);
        float4 d0 = *(const float4*)(dlt + i);
        float4 d1 = *(const float4*)(dlt + tstride + i);
        ushort4 o;
        o.x = f2b(b.x + l0 * d0.x + l1 * d1.x);
        o.y = f2b(b.y + l0 * d0.y + l1 * d1.y);
        o.z = f2b(b.z + l0 * d0.z + l1 * d1.z);
        o.w = f2b(b.w + l0 * d0.w + l1 * d1.w);
        *(ushort4*)(out + i) = o;
    }
}

// merge + transpose: in (K x N fp32), out (N x K bf16). 64x64 tiles.
__global__ __launch_bounds__(256) void mt_kernel(const float* __restrict__ in,
                                                 const float* __restrict__ din, size_t tstride,
                                                 const float* __restrict__ lam,
                                                 unsigned short* __restrict__ outT,
                                                 int K, int N) {
    __shared__ float T[64][65];
    float l0 = lam[0], l1 = lam[1];
    int n0 = blockIdx.x * 64, k0 = blockIdx.y * 64;
    int tr = threadIdx.x >> 4;   // 0..15
    int tc = threadIdx.x & 15;   // 0..15
    #pragma unroll
    for (int rep = 0; rep < 4; rep++) {
        int kk = tr + rep * 16;
        size_t idx = (size_t)(k0 + kk) * N + n0 + tc * 4;
        float4 b = *(const float4*)(in + idx);
        float4 d0 = *(const float4*)(din + idx);
        float4 d1 = *(const float4*)(din + tstride + idx);
        T[kk][tc * 4 + 0] = b.x + l0 * d0.x + l1 * d1.x;
        T[kk][tc * 4 + 1] = b.y + l0 * d0.y + l1 * d1.y;
        T[kk][tc * 4 + 2] = b.z + l0 * d0.z + l1 * d1.z;
        T[kk][tc * 4 + 3] = b.w + l0 * d0.w + l1 * d1.w;
    }
    __syncthreads();
    #pragma unroll
    for (int rep = 0; rep < 4; rep++) {
        int n = tr + rep * 16;
        int kc = tc * 4;
        ushort4 o;
        o.x = f2b(T[kc + 0][n]);
        o.y = f2b(T[kc + 1][n]);
        o.z = f2b(T[kc + 2][n]);
        o.w = f2b(T[kc + 3][n]);
        *(ushort4*)(outT + (size_t)(n0 + n) * K + k0 + kc) = o;
    }
}

// ---------------- embedding / LN ----------------

__global__ void embed_kernel(const int* __restrict__ ids, const unsigned short* __restrict__ embm,
                             float* __restrict__ h) {
    int row = blockIdx.x;
    int id = ids[row];
    const unsigned short* src = embm + (size_t)id * D_;
    float* dst = h + (size_t)row * D_;
    for (int d = threadIdx.x; d < D_; d += 256) dst[d] = b2f(src[d]);
}

// h fp32 in -> a bf16 out
__global__ __launch_bounds__(256) void ln_kernel(const float* __restrict__ x,
                                                 const float* __restrict__ g,
                                                 unsigned short* __restrict__ out) {
    __shared__ float sred[8];
    int row = blockIdx.x;
    const float* xr = x + (size_t)row * D_;
    float s = 0.f, ss = 0.f;
    for (int d = threadIdx.x; d < D_; d += 256) { float v = xr[d]; s += v; ss += v * v; }
    for (int o = 32; o > 0; o >>= 1) { s += __shfl_down(s, o); ss += __shfl_down(ss, o); }
    int lane = threadIdx.x & 63, wid = threadIdx.x >> 6;
    if (lane == 0) { sred[wid] = s; sred[4 + wid] = ss; }
    __syncthreads();
    if (threadIdx.x == 0) {
        sred[0] = sred[0] + sred[1] + sred[2] + sred[3];
        sred[4] = sred[4] + sred[5] + sred[6] + sred[7];
    }
    __syncthreads();
    float mu = sred[0] * (1.0f / D_);
    float var = sred[4] * (1.0f / D_) - mu * mu;
    float r = rsqrtf(var + 1e-5f);
    unsigned short* orow = out + (size_t)row * D_;
    for (int d = threadIdx.x; d < D_; d += 256) orow[d] = f2b((xr[d] - mu) * r * g[d]);
}

// ---------------- MFMA GEMM ----------------
// C[M,N] = A[M,K] @ Bt[N,K]^T, bf16 inputs, fp32 accum.
// MODE 0: Cf = acc (fp32). 1: Cf += acc (residual). 2: Cb = bf16(acc). 3: Cb = bf16(gelu(acc)).
// 128x128 tile, BK=32, 256 thr = 4 waves, wave does 64x64 via 4x4 MFMA 16x16x32 tiles.
template<int MODE>
__global__ __launch_bounds__(256) void gemm_mfma(const unsigned short* __restrict__ A,
                                                 const unsigned short* __restrict__ Bt,
                                                 float* __restrict__ Cf,
                                                 unsigned short* __restrict__ Cb,
                                                 int M, int N, int K) {
    __shared__ unsigned short As[128 * 32];
    __shared__ unsigned short Bs[128 * 32];
    int bm = blockIdx.y * 128, bn = blockIdx.x * 128;
    int tid = threadIdx.x;
    int w = tid >> 6, lane = tid & 63;
    int wm = (w & 1) * 64, wn = (w >> 1) * 64;
    int l15 = lane & 15, quad = lane >> 4;
    f32x4 acc[4][4] = {};

    int arow = w * 32 + (lane >> 2);
    int aseg = (lane & 3) * 8;
    const unsigned short* gA0 = A + (size_t)(bm + arow) * K + aseg;
    const unsigned short* gA1 = A + (size_t)(bm + arow + 16) * K + aseg;
    const unsigned short* gB0 = Bt + (size_t)(bn + arow) * K + aseg;
    const unsigned short* gB1 = Bt + (size_t)(bn + arow + 16) * K + aseg;
    unsigned short* lA0 = &As[arow * 32 + aseg];
    unsigned short* lA1 = &As[(arow + 16) * 32 + aseg];
    unsigned short* lB0 = &Bs[arow * 32 + aseg];
    unsigned short* lB1 = &Bs[(arow + 16) * 32 + aseg];

    for (int k0 = 0; k0 < K; k0 += 32) {
        gld16(gA0 + k0, lA0);
        gld16(gA1 + k0, lA1);
        gld16(gB0 + k0, lB0);
        gld16(gB1 + k0, lB1);
        __syncthreads();
        short8 af[4], bfm[4];
        #pragma unroll
        for (int i = 0; i < 4; i++) af[i] = *(const short8*)&As[(wm + i * 16 + l15) * 32 + quad * 8];
        #pragma unroll
        for (int j = 0; j < 4; j++) bfm[j] = *(const short8*)&Bs[(wn + j * 16 + l15) * 32 + quad * 8];
        #pragma unroll
        for (int i = 0; i < 4; i++)
            #pragma unroll
            for (int j = 0; j < 4; j++)
                acc[i][j] = __builtin_amdgcn_mfma_f32_16x16x32_bf16(af[i], bfm[j], acc[i][j], 0, 0, 0);
        __syncthreads();
    }

    #pragma unroll
    for (int i = 0; i < 4; i++) {
        int row = bm + wm + i * 16 + quad * 4;
        #pragma unroll
        for (int j = 0; j < 4; j++) {
            int col = bn + wn + j * 16 + l15;
            #pragma unroll
            for (int r = 0; r < 4; r++) {
                size_t idx = (size_t)(row + r) * N + col;
                float v = acc[i][j][r];
                if (MODE == 0) Cf[idx] = v;
                if (MODE == 1) Cf[idx] += v;
                if (MODE == 2) Cb[idx] = f2b(v);
                if (MODE == 3) {
                    float c = 0.7978845608028654f * (v + 0.044715f * v * v * v);
                    Cb[idx] = f2b(0.5f * v * (1.0f + tanhf(c)));
                }
            }
        }
    }
}

// ---------------- flash attention (MFMA) ----------------
// grid (qtiles=16, H, B), block 256 = 4 waves. Q tile 64 rows; wave w owns rows
// w*16..w*16+15. K tiles of 64, online softmax in MFMA C-layout registers.
// LDS: K rows bf16 [64][72] (pad 72 -> conflict-optimal b128 reads),
//      V^T f32 [64][68] (transpose-staged like old Kt; 16B-aligned packed reads),
//      P bf16 per-wave [16][72].
#define UNPACK8(u, dst) { (dst)[0]=blo((u).x);(dst)[1]=bhi((u).x);(dst)[2]=blo((u).y);(dst)[3]=bhi((u).y);(dst)[4]=blo((u).z);(dst)[5]=bhi((u).z);(dst)[6]=blo((u).w);(dst)[7]=bhi((u).w); }

__global__ __launch_bounds__(256) void attn_kernel(const unsigned short* __restrict__ qkv,
                                                   unsigned short* __restrict__ attno) {
    int qt = blockIdx.x, h = blockIdx.y, b = blockIdx.z;
    int tid = threadIdx.x;
    int w = tid >> 6, lane = tid & 63;
    int l15 = lane & 15, quad = lane >> 4;

    __shared__ unsigned short Ks[64][72];
    __shared__ float Vt[64][68];
    __shared__ unsigned short Ps[4][16][72];

    // Q fragments in registers: A-frag rows = l15 (wave-local q row), k = kk*32+quad*8
    short8 aq[2];
    {
        const unsigned short* gq = qkv + (size_t)(b * S_ + qt * 64 + w * 16 + l15) * D3_ + h * HD_ + quad * 8;
        aq[0] = *(const short8*)(gq);
        aq[1] = *(const short8*)(gq + 32);
    }

    f32x4 oacc[4] = {};
    float m_i[4] = {-1e30f, -1e30f, -1e30f, -1e30f};
    float l_i[4] = {0.f, 0.f, 0.f, 0.f};

    int krr = tid >> 3, kseg = tid & 7;        // K staging: 2 rows/thread
    int vrr = tid >> 2, vd0 = (tid & 3) * 16;  // V staging: 1 row, 16 dims/thread

    for (int kt = 0; kt <= qt; kt++) {
        __syncthreads();   // prior-iteration LDS reads complete
        // stage K rows (bf16 pass-through, b128 writes)
        {
            const unsigned short* gk = qkv + (size_t)(b * S_ + kt * 64 + krr) * D3_ + D_ + h * HD_ + kseg * 8;
            uint4 u0 = *(const uint4*)gk;
            uint4 u1 = *(const uint4*)(gk + (size_t)32 * D3_);
            *(uint4*)&Ks[krr][kseg * 8] = u0;
            *(uint4*)&Ks[krr + 32][kseg * 8] = u1;
        }
        // stage V transposed (f32)
        {
            const unsigned short* gv = qkv + (size_t)(b * S_ + kt * 64 + vrr) * D3_ + 2 * D_ + h * HD_ + vd0;
            uint4 v0 = *(const uint4*)gv;
            uint4 v1 = *(const uint4*)(gv + 8);
            float tmp[16];
            UNPACK8(v0, tmp); UNPACK8(v1, tmp + 8);
            #pragma unroll
            for (int u = 0; u < 16; u++) Vt[vd0 + u][vrr] = tmp[u];
        }
        __syncthreads();

        // QK^T: wave computes S[16 q][64 k] as 4 col-tiles x 2 k-steps
        f32x4 sc[4] = {};
        #pragma unroll
        for (int kk = 0; kk < 2; kk++)
            #pragma unroll
            for (int j = 0; j < 4; j++) {
                short8 bk = *(const short8*)&Ks[j * 16 + l15][kk * 32 + quad * 8];
                sc[j] = __builtin_amdgcn_mfma_f32_16x16x32_bf16(aq[kk], bk, sc[j], 0, 0, 0);
            }

        // scale + causal mask (C-layout: row = quad*4+r, col = j*16+l15)
        bool diag = (kt == qt);
        #pragma unroll
        for (int j = 0; j < 4; j++)
            #pragma unroll
            for (int r = 0; r < 4; r++) {
                float v = sc[j][r] * 0.125f;
                if (diag && (j * 16 + l15) > (w * 16 + quad * 4 + r)) v = -1e30f;
                sc[j][r] = v;
            }

        // online softmax per q-row; row spread over 16 lanes (same quad) x 4 col-tiles
        #pragma unroll
        for (int r = 0; r < 4; r++) {
            float rm = fmaxf(fmaxf(sc[0][r], sc[1][r]), fmaxf(sc[2][r], sc[3][r]));
            rm = fmaxf(rm, __shfl_xor(rm, 1));
            rm = fmaxf(rm, __shfl_xor(rm, 2));
            rm = fmaxf(rm, __shfl_xor(rm, 4));
            rm = fmaxf(rm, __shfl_xor(rm, 8));
            float mnew = fmaxf(m_i[r], rm);
            float alpha = __expf(m_i[r] - mnew);
            float p0 = __expf(sc[0][r] - mnew);
            float p1 = __expf(sc[1][r] - mnew);
            float p2 = __expf(sc[2][r] - mnew);
            float p3 = __expf(sc[3][r] - mnew);
            float ls = p0 + p1 + p2 + p3;
            ls += __shfl_xor(ls, 1);
            ls += __shfl_xor(ls, 2);
            ls += __shfl_xor(ls, 4);
            ls += __shfl_xor(ls, 8);
            l_i[r] = l_i[r] * alpha + ls;
            m_i[r] = mnew;
            oacc[0][r] *= alpha; oacc[1][r] *= alpha;
            oacc[2][r] *= alpha; oacc[3][r] *= alpha;
            Ps[w][quad * 4 + r][ 0 + l15] = f2b(p0);
            Ps[w][quad * 4 + r][16 + l15] = f2b(p1);
            Ps[w][quad * 4 + r][32 + l15] = f2b(p2);
            Ps[w][quad * 4 + r][48 + l15] = f2b(p3);
        }

        // PV: O[16 q][64 d] += P[16 q][64 k] * V[64 k][64 d]
        #pragma unroll
        for (int kk = 0; kk < 2; kk++) {
            short8 pa = *(const short8*)&Ps[w][l15][kk * 32 + quad * 8];
            #pragma unroll
            for (int j = 0; j < 4; j++) {
                const float* vp = &Vt[j * 16 + l15][kk * 32 + quad * 8];
                f32x4 f0 = *(const f32x4*)vp;
                f32x4 f1 = *(const f32x4*)(vp + 4);
                // lossless re-pack to bf16 (values came from bf16, low mantissa is zero)
                unsigned int b0 = (__float_as_uint(f0[1]) & 0xffff0000u) | (__float_as_uint(f0[0]) >> 16);
                unsigned int b1 = (__float_as_uint(f0[3]) & 0xffff0000u) | (__float_as_uint(f0[2]) >> 16);
                unsigned int b2 = (__float_as_uint(f1[1]) & 0xffff0000u) | (__float_as_uint(f1[0]) >> 16);
                unsigned int b3 = (__float_as_uint(f1[3]) & 0xffff0000u) | (__float_as_uint(f1[2]) >> 16);
                union { uint4v u; short8 s; } cvt;
                cvt.u = (uint4v){b0, b1, b2, b3};
                oacc[j] = __builtin_amdgcn_mfma_f32_16x16x32_bf16(pa, cvt.s, oacc[j], 0, 0, 0);
            }
        }
    }

    // epilogue: rows = qt*64 + w*16 + quad*4 + r, cols = j*16 + l15
    #pragma unroll
    for (int r = 0; r < 4; r++) {
        float inv = 1.0f / l_i[r];
        size_t row = (size_t)(b * S_ + qt * 64 + w * 16 + quad * 4 + r);
        #pragma unroll
        for (int j = 0; j < 4; j++)
            attno[row * D_ + h * HD_ + j * 16 + l15] = f2b(oacc[j][r] * inv);
    }
}

// ---------------- loss ----------------

__global__ void loss_init_kernel(float* rm, float* rl, float* rtl) {
    int i = blockIdx.x * blockDim.x + threadIdx.x;
    if (i < BS_) { rm[i] = -1e30f; rl[i] = 0.f; rtl[i] = 0.f; }
}

__global__ __launch_bounds__(256) void loss_chunk_kernel(const float* __restrict__ lg,
                                                         const int* __restrict__ labels,
                                                         float* rm, float* rl, float* rtl,
                                                         int v0) {
    int row = blockIdx.x;
    const float* lr = lg + (size_t)row * VC_;
    int tid = threadIdx.x;
    __shared__ float sred[8];
    float m = -1e30f;
    for (int j = tid; j < VC_; j += 256) m = fmaxf(m, lr[j]);
    for (int o = 32; o > 0; o >>= 1) m = fmaxf(m, __shfl_down(m, o));
    int lane = tid & 63, wid = tid >> 6;
    if (lane == 0) sred[wid] = m;
    __syncthreads();
    if (tid == 0) sred[0] = fmaxf(fmaxf(sred[0], sred[1]), fmaxf(sred[2], sred[3]));
    __syncthreads();
    float cm = sred[0];
    float s = 0.f;
    for (int j = tid; j < VC_; j += 256) s += __expf(lr[j] - cm);
    for (int o = 32; o > 0; o >>= 1) s += __shfl_down(s, o);
    if (lane == 0) sred[4 + wid] = s;
    __syncthreads();
    if (tid == 0) {
        float cs = sred[4] + sred[5] + sred[6] + sred[7];
        float om = rm[row], ol = rl[row];
        float nm = fmaxf(om, cm);
        rl[row] = ol * __expf(om - nm) + cs * __expf(cm - nm);
        rm[row] = nm;
        int b = row / S_, spos = row % S_;
        if (spos < S_ - 1) {
            int tgt = labels[b * S_ + spos + 1];
            if (tgt >= v0 && tgt < v0 + VC_) rtl[row] = lr[tgt - v0];
        }
    }
}

__global__ __launch_bounds__(256) void loss_final_kernel(const float* rm, const float* rl,
                                                         const float* rtl, float* out) {
    __shared__ float sred[4];
    float s = 0.f;
    for (int row = threadIdx.x; row < BS_; row += 256) {
        int spos = row % S_;
        if (spos < S_ - 1) s += (rm[row] + logf(rl[row])) - rtl[row];
    }
    for (int o = 32; o > 0; o >>= 1) s += __shfl_down(s, o);
    int lane = threadIdx.x & 63, wid = threadIdx.x >> 6;
    if (lane == 0) sred[wid] = s;
    __syncthreads();
    if (threadIdx.x == 0)
        out[0] = (sred[0] + sred[1] + sred[2] + sred[3]) * (1.0f / (B_ * (S_ - 1)));
}

// ---------------- launch ----------------

extern "C" void kernel_launch(void* const* d_in, const int* in_sizes, int n_in,
                              void* d_out, int out_size, void* d_ws, size_t ws_size,
                              hipStream_t stream) {
    const int*   ids    = (const int*)d_in[0];
    const int*   labels = (const int*)d_in[1];
    const float* lam    = (const float*)d_in[2];
    const float* emb    = (const float*)d_in[3];
    const float* Wqkv   = (const float*)d_in[4];
    const float* Wo     = (const float*)d_in[5];
    const float* W1     = (const float*)d_in[6];
    const float* W2     = (const float*)d_in[7];
    const float* g1     = (const float*)d_in[8];
    const float* g2     = (const float*)d_in[9];
    const float* gf     = (const float*)d_in[10];
    const float* dEmb   = (const float*)d_in[11];
    const float* dWqkv  = (const float*)d_in[12];
    const float* dWo    = (const float*)d_in[13];
    const float* dW1    = (const float*)d_in[14];
    const float* dW2    = (const float*)d_in[15];
    const float* dG1    = (const float*)d_in[16];
    const float* dG2    = (const float*)d_in[17];
    const float* dGf    = (const float*)d_in[18];
    float* out = (float*)d_out;

    char* wsb = (char*)d_ws;
    size_t off = 0;
    auto alloc = [&](size_t bytes) {
        off = (off + 255) & ~(size_t)255;
        void* p = wsb + off;
        off += bytes;
        return p;
    };
    unsigned short* embm  = (unsigned short*)alloc((size_t)V_ * D_ * 2);
    unsigned short* WqkvT = (unsigned short*)alloc((size_t)L_ * D3_ * D_ * 2);
    unsigned short* WoT   = (unsigned short*)alloc((size_t)L_ * D_ * D_ * 2);
    unsigned short* W1T   = (unsigned short*)alloc((size_t)L_ * DFF_ * D_ * 2);
    unsigned short* W2T   = (unsigned short*)alloc((size_t)L_ * D_ * DFF_ * 2);
    float* g1m = (float*)alloc((size_t)L_ * D_ * 4);
    float* g2m = (float*)alloc((size_t)L_ * D_ * 4);
    float* gfm = (float*)alloc((size_t)D_ * 4);
    float* h   = (float*)alloc((size_t)BS_ * D_ * 4);
    unsigned short* a_bf  = (unsigned short*)alloc((size_t)BS_ * D_ * 2);
    unsigned short* qkv   = (unsigned short*)alloc((size_t)BS_ * D3_ * 2);
    unsigned short* attno = (unsigned short*)alloc((size_t)BS_ * D_ * 2);
    unsigned short* ffh   = (unsigned short*)alloc((size_t)BS_ * DFF_ * 2);
    float* lchunk = (float*)alloc((size_t)BS_ * VC_ * 4);
    float* rm  = (float*)alloc(BS_ * 4);
    float* rl  = (float*)alloc(BS_ * 4);
    float* rtl = (float*)alloc(BS_ * 4);

    // ---- merges ----
    merge_bf16_kernel<<<4096, 256, 0, stream>>>(emb, dEmb, (size_t)V_ * D_, lam, embm, (size_t)V_ * D_ / 4);
    for (int l = 0; l < L_; l++) {
        mt_kernel<<<dim3(D3_ / 64, D_ / 64), 256, 0, stream>>>(
            Wqkv + (size_t)l * D_ * D3_, dWqkv + (size_t)l * D_ * D3_, (size_t)L_ * D_ * D3_,
            lam, WqkvT + (size_t)l * D3_ * D_, D_, D3_);
        mt_kernel<<<dim3(D_ / 64, D_ / 64), 256, 0, stream>>>(
            Wo + (size_t)l * D_ * D_, dWo + (size_t)l * D_ * D_, (size_t)L_ * D_ * D_,
            lam, WoT + (size_t)l * D_ * D_, D_, D_);
        mt_kernel<<<dim3(DFF_ / 64, D_ / 64), 256, 0, stream>>>(
            W1 + (size_t)l * D_ * DFF_, dW1 + (size_t)l * D_ * DFF_, (size_t)L_ * D_ * DFF_,
            lam, W1T + (size_t)l * DFF_ * D_, D_, DFF_);
        mt_kernel<<<dim3(D_ / 64, DFF_ / 64), 256, 0, stream>>>(
            W2 + (size_t)l * DFF_ * D_, dW2 + (size_t)l * DFF_ * D_, (size_t)L_ * DFF_ * D_,
            lam, W2T + (size_t)l * D_ * DFF_, DFF_, D_);
    }
    merge_f32_kernel<<<8, 256, 0, stream>>>(g1, dG1, (size_t)L_ * D_, lam, g1m, L_ * D_);
    merge_f32_kernel<<<8, 256, 0, stream>>>(g2, dG2, (size_t)L_ * D_, lam, g2m, L_ * D_);
    merge_f32_kernel<<<4, 256, 0, stream>>>(gf, dGf, (size_t)D_, lam, gfm, D_);

    // ---- embedding ----
    embed_kernel<<<BS_, 256, 0, stream>>>(ids, embm, h);

    // ---- layers ----
    for (int l = 0; l < L_; l++) {
        ln_kernel<<<BS_, 256, 0, stream>>>(h, g1m + l * D_, a_bf);
        gemm_mfma<2><<<dim3(D3_ / 128, BS_ / 128), 256, 0, stream>>>(
            a_bf, WqkvT + (size_t)l * D3_ * D_, nullptr, qkv, BS_, D3_, D_);
        attn_kernel<<<dim3(S_ / 64, H_, B_), 256, 0, stream>>>(qkv, attno);
        gemm_mfma<1><<<dim3(D_ / 128, BS_ / 128), 256, 0, stream>>>(
            attno, WoT + (size_t)l * D_ * D_, h, nullptr, BS_, D_, D_);
        ln_kernel<<<BS_, 256, 0, stream>>>(h, g2m + l * D_, a_bf);
        gemm_mfma<3><<<dim3(DFF_ / 128, BS_ / 128), 256, 0, stream>>>(
            a_bf, W1T + (size_t)l * DFF_ * D_, nullptr, ffh, BS_, DFF_, D_);
        gemm_mfma<1><<<dim3(D_ / 128, BS_ / 128), 256, 0, stream>>>(
            ffh, W2T + (size_t)l * D_ * DFF_, h, nullptr, BS_, D_, DFF_);
    }

    // ---- final LN ----
    ln_kernel<<<BS_, 256, 0, stream>>>(h, gfm, a_bf);

    // ---- logits + loss ----
    loss_init_kernel<<<(BS_ + 255) / 256, 256, 0, stream>>>(rm, rl, rtl);
    for (int c = 0; c < V_ / VC_; c++) {
        int v0 = c * VC_;
        gemm_mfma<0><<<dim3(VC_ / 128, BS_ / 128), 256, 0, stream>>>(
            a_bf, embm + (size_t)v0 * D_, lchunk, nullptr, BS_, VC_, D_);
        loss_chunk_kernel<<<BS_, 256, 0, stream>>>(lchunk, labels, rm, rl, rtl, v0);
    }
    loss_final_kernel<<<1, 256, 0, stream>>>(rm, rl, rtl, out);
}

// Round 3
// 1444.238 us; speedup vs baseline: 1.2424x; 1.1185x over previous
//
#include <hip/hip_runtime.h>
#include <math.h>

#define L_ 2
#define D_ 1024
#define H_ 16
#define HD_ 64
#define DFF_ 4096
#define V_ 32000
#define B_ 2
#define S_ 1024
#define BS_ (B_*S_)
#define D3_ (3*D_)
#define NT_ (V_/128)   // 250 column tiles for the fused logits GEMM

typedef __attribute__((ext_vector_type(8))) short short8;
typedef __attribute__((ext_vector_type(4))) float f32x4;
typedef __attribute__((ext_vector_type(4))) unsigned int uint4v;

__device__ __forceinline__ float b2f(unsigned short u) {
    return __uint_as_float(((unsigned int)u) << 16);
}
__device__ __forceinline__ unsigned short f2b(float f) {
    unsigned int u = __float_as_uint(f);
    return (unsigned short)((u + 0x7fffu + ((u >> 16) & 1u)) >> 16);
}
__device__ __forceinline__ float blo(unsigned int u) { return __uint_as_float(u << 16); }
__device__ __forceinline__ float bhi(unsigned int u) { return __uint_as_float(u & 0xffff0000u); }

__device__ __forceinline__ void gld16(const void* g, void* l) {
    __builtin_amdgcn_global_load_lds(
        (const __attribute__((address_space(1))) unsigned int*)g,
        (__attribute__((address_space(3))) unsigned int*)l, 16, 0, 0);
}

// ---------------- merges ----------------

__global__ void merge_f32_kernel(const float* __restrict__ base, const float* __restrict__ dlt,
                                 size_t tstride, const float* __restrict__ lam,
                                 float* __restrict__ out, int n) {
    float l0 = lam[0], l1 = lam[1];
    for (int i = blockIdx.x * blockDim.x + threadIdx.x; i < n; i += gridDim.x * blockDim.x)
        out[i] = base[i] + l0 * dlt[i] + l1 * dlt[i + tstride];
}

__global__ void merge_bf16_kernel(const float* __restrict__ base, const float* __restrict__ dlt,
                                  size_t tstride, const float* __restrict__ lam,
                                  unsigned short* __restrict__ out, size_t n4) {
    float l0 = lam[0], l1 = lam[1];
    for (size_t q = blockIdx.x * blockDim.x + threadIdx.x; q < n4; q += (size_t)gridDim.x * blockDim.x) {
        size_t i = q * 4;
        float4 b = *(const float4*)(base + i);
        float4 d0 = *(const float4*)(dlt + i);
        float4 d1 = *(const float4*)(dlt + tstride + i);
        ushort4 o;
        o.x = f2b(b.x + l0 * d0.x + l1 * d1.x);
        o.y = f2b(b.y + l0 * d0.y + l1 * d1.y);
        o.z = f2b(b.z + l0 * d0.z + l1 * d1.z);
        o.w = f2b(b.w + l0 * d0.w + l1 * d1.w);
        *(ushort4*)(out + i) = o;
    }
}

// merge + transpose: in (K x N fp32), out (N x K bf16). 64x64 tiles.
__global__ __launch_bounds__(256) void mt_kernel(const float* __restrict__ in,
                                                 const float* __restrict__ din, size_t tstride,
                                                 const float* __restrict__ lam,
                                                 unsigned short* __restrict__ outT,
                                                 int K, int N) {
    __shared__ float T[64][65];
    float l0 = lam[0], l1 = lam[1];
    int n0 = blockIdx.x * 64, k0 = blockIdx.y * 64;
    int tr = threadIdx.x >> 4;   // 0..15
    int tc = threadIdx.x & 15;   // 0..15
    #pragma unroll
    for (int rep = 0; rep < 4; rep++) {
        int kk = tr + rep * 16;
        size_t idx = (size_t)(k0 + kk) * N + n0 + tc * 4;
        float4 b = *(const float4*)(in + idx);
        float4 d0 = *(const float4*)(din + idx);
        float4 d1 = *(const float4*)(din + tstride + idx);
        T[kk][tc * 4 + 0] = b.x + l0 * d0.x + l1 * d1.x;
        T[kk][tc * 4 + 1] = b.y + l0 * d0.y + l1 * d1.y;
        T[kk][tc * 4 + 2] = b.z + l0 * d0.z + l1 * d1.z;
        T[kk][tc * 4 + 3] = b.w + l0 * d0.w + l1 * d1.w;
    }
    __syncthreads();
    #pragma unroll
    for (int rep = 0; rep < 4; rep++) {
        int n = tr + rep * 16;
        int kc = tc * 4;
        ushort4 o;
        o.x = f2b(T[kc + 0][n]);
        o.y = f2b(T[kc + 1][n]);
        o.z = f2b(T[kc + 2][n]);
        o.w = f2b(T[kc + 3][n]);
        *(ushort4*)(outT + (size_t)(n0 + n) * K + k0 + kc) = o;
    }
}

// ---------------- embedding / LN ----------------

__global__ void embed_kernel(const int* __restrict__ ids, const unsigned short* __restrict__ embm,
                             float* __restrict__ h) {
    int row = blockIdx.x;
    int id = ids[row];
    const unsigned short* src = embm + (size_t)id * D_;
    float* dst = h + (size_t)row * D_;
    for (int d = threadIdx.x; d < D_; d += 256) dst[d] = b2f(src[d]);
}

// h fp32 in -> a bf16 out
__global__ __launch_bounds__(256) void ln_kernel(const float* __restrict__ x,
                                                 const float* __restrict__ g,
                                                 unsigned short* __restrict__ out) {
    __shared__ float sred[8];
    int row = blockIdx.x;
    const float* xr = x + (size_t)row * D_;
    float s = 0.f, ss = 0.f;
    for (int d = threadIdx.x; d < D_; d += 256) { float v = xr[d]; s += v; ss += v * v; }
    for (int o = 32; o > 0; o >>= 1) { s += __shfl_down(s, o); ss += __shfl_down(ss, o); }
    int lane = threadIdx.x & 63, wid = threadIdx.x >> 6;
    if (lane == 0) { sred[wid] = s; sred[4 + wid] = ss; }
    __syncthreads();
    if (threadIdx.x == 0) {
        sred[0] = sred[0] + sred[1] + sred[2] + sred[3];
        sred[4] = sred[4] + sred[5] + sred[6] + sred[7];
    }
    __syncthreads();
    float mu = sred[0] * (1.0f / D_);
    float var = sred[4] * (1.0f / D_) - mu * mu;
    float r = rsqrtf(var + 1e-5f);
    unsigned short* orow = out + (size_t)row * D_;
    for (int d = threadIdx.x; d < D_; d += 256) orow[d] = f2b((xr[d] - mu) * r * g[d]);
}

// ---------------- MFMA GEMM ----------------
// C[M,N] = A[M,K] @ Bt[N,K]^T, bf16 inputs, fp32 accum.
// MODE 1: Cf += acc (residual). 2: Cb = bf16(acc). 3: Cb = bf16(gelu(acc)).
// 128x128 tile, BK=32, 256 thr = 4 waves, wave does 64x64 via 4x4 MFMA 16x16x32 tiles.
template<int MODE>
__global__ __launch_bounds__(256) void gemm_mfma(const unsigned short* __restrict__ A,
                                                 const unsigned short* __restrict__ Bt,
                                                 float* __restrict__ Cf,
                                                 unsigned short* __restrict__ Cb,
                                                 int M, int N, int K) {
    __shared__ unsigned short As[128 * 32];
    __shared__ unsigned short Bs[128 * 32];
    int bm = blockIdx.y * 128, bn = blockIdx.x * 128;
    int tid = threadIdx.x;
    int w = tid >> 6, lane = tid & 63;
    int wm = (w & 1) * 64, wn = (w >> 1) * 64;
    int l15 = lane & 15, quad = lane >> 4;
    f32x4 acc[4][4] = {};

    int arow = w * 32 + (lane >> 2);
    int aseg = (lane & 3) * 8;
    const unsigned short* gA0 = A + (size_t)(bm + arow) * K + aseg;
    const unsigned short* gA1 = A + (size_t)(bm + arow + 16) * K + aseg;
    const unsigned short* gB0 = Bt + (size_t)(bn + arow) * K + aseg;
    const unsigned short* gB1 = Bt + (size_t)(bn + arow + 16) * K + aseg;
    unsigned short* lA0 = &As[arow * 32 + aseg];
    unsigned short* lA1 = &As[(arow + 16) * 32 + aseg];
    unsigned short* lB0 = &Bs[arow * 32 + aseg];
    unsigned short* lB1 = &Bs[(arow + 16) * 32 + aseg];

    for (int k0 = 0; k0 < K; k0 += 32) {
        gld16(gA0 + k0, lA0);
        gld16(gA1 + k0, lA1);
        gld16(gB0 + k0, lB0);
        gld16(gB1 + k0, lB1);
        __syncthreads();
        short8 af[4], bfm[4];
        #pragma unroll
        for (int i = 0; i < 4; i++) af[i] = *(const short8*)&As[(wm + i * 16 + l15) * 32 + quad * 8];
        #pragma unroll
        for (int j = 0; j < 4; j++) bfm[j] = *(const short8*)&Bs[(wn + j * 16 + l15) * 32 + quad * 8];
        #pragma unroll
        for (int i = 0; i < 4; i++)
            #pragma unroll
            for (int j = 0; j < 4; j++)
                acc[i][j] = __builtin_amdgcn_mfma_f32_16x16x32_bf16(af[i], bfm[j], acc[i][j], 0, 0, 0);
        __syncthreads();
    }

    #pragma unroll
    for (int i = 0; i < 4; i++) {
        int row = bm + wm + i * 16 + quad * 4;
        #pragma unroll
        for (int j = 0; j < 4; j++) {
            int col = bn + wn + j * 16 + l15;
            #pragma unroll
            for (int r = 0; r < 4; r++) {
                size_t idx = (size_t)(row + r) * N + col;
                float v = acc[i][j][r];
                if (MODE == 1) Cf[idx] += v;
                if (MODE == 2) Cb[idx] = f2b(v);
                if (MODE == 3) {
                    float c = 0.7978845608028654f * (v + 0.044715f * v * v * v);
                    Cb[idx] = f2b(0.5f * v * (1.0f + tanhf(c)));
                }
            }
        }
    }
}

// ---------------- fused logits GEMM + split-softmax stats ----------------
// A[BS_,D_] @ embm[V_,D_]^T. No logits materialized: per 128-col tile, emit
// per-row (max, sum_exp) partials and snipe the target logit on the fly.
__global__ __launch_bounds__(256) void gemm_loss_kernel(const unsigned short* __restrict__ A,
                                                        const unsigned short* __restrict__ Bt,
                                                        const int* __restrict__ labels,
                                                        float2* __restrict__ part, // [BS_][NT_]
                                                        float* __restrict__ rtl) {
    __shared__ unsigned short As[128 * 32];
    __shared__ unsigned short Bs[128 * 32];
    __shared__ float Ms[128][2];
    __shared__ float Ls[128][2];
    __shared__ int tgts[128];
    const int K = D_;
    int bm = blockIdx.y * 128, bn = blockIdx.x * 128;
    int tid = threadIdx.x;
    int w = tid >> 6, lane = tid & 63;
    int wm = (w & 1) * 64, wn = (w >> 1) * 64;
    int l15 = lane & 15, quad = lane >> 4;
    f32x4 acc[4][4] = {};

    int arow = w * 32 + (lane >> 2);
    int aseg = (lane & 3) * 8;
    const unsigned short* gA0 = A + (size_t)(bm + arow) * K + aseg;
    const unsigned short* gA1 = A + (size_t)(bm + arow + 16) * K + aseg;
    const unsigned short* gB0 = Bt + (size_t)(bn + arow) * K + aseg;
    const unsigned short* gB1 = Bt + (size_t)(bn + arow + 16) * K + aseg;
    unsigned short* lA0 = &As[arow * 32 + aseg];
    unsigned short* lA1 = &As[(arow + 16) * 32 + aseg];
    unsigned short* lB0 = &Bs[arow * 32 + aseg];
    unsigned short* lB1 = &Bs[(arow + 16) * 32 + aseg];

    for (int k0 = 0; k0 < K; k0 += 32) {
        gld16(gA0 + k0, lA0);
        gld16(gA1 + k0, lA1);
        gld16(gB0 + k0, lB0);
        gld16(gB1 + k0, lB1);
        __syncthreads();
        short8 af[4], bfm[4];
        #pragma unroll
        for (int i = 0; i < 4; i++) af[i] = *(const short8*)&As[(wm + i * 16 + l15) * 32 + quad * 8];
        #pragma unroll
        for (int j = 0; j < 4; j++) bfm[j] = *(const short8*)&Bs[(wn + j * 16 + l15) * 32 + quad * 8];
        #pragma unroll
        for (int i = 0; i < 4; i++)
            #pragma unroll
            for (int j = 0; j < 4; j++)
                acc[i][j] = __builtin_amdgcn_mfma_f32_16x16x32_bf16(af[i], bfm[j], acc[i][j], 0, 0, 0);
        __syncthreads();
    }

    // stage target ids for this block's 128 rows
    if (tid < 128) {
        int rg = bm + tid;
        int b = rg / S_, spos = rg % S_;
        tgts[tid] = (spos < S_ - 1) ? labels[b * S_ + spos + 1] : -1;
    }
    __syncthreads();

    // per-row (max, sumexp) over this wave's 64 cols; row spread over 16 lanes
    #pragma unroll
    for (int i = 0; i < 4; i++) {
        #pragma unroll
        for (int r = 0; r < 4; r++) {
            int rowl = wm + i * 16 + quad * 4 + r;
            int tgt = tgts[rowl];
            float m = fmaxf(fmaxf(acc[i][0][r], acc[i][1][r]), fmaxf(acc[i][2][r], acc[i][3][r]));
            m = fmaxf(m, __shfl_xor(m, 1));
            m = fmaxf(m, __shfl_xor(m, 2));
            m = fmaxf(m, __shfl_xor(m, 4));
            m = fmaxf(m, __shfl_xor(m, 8));
            float l = 0.f;
            #pragma unroll
            for (int j = 0; j < 4; j++) {
                float v = acc[i][j][r];
                l += __expf(v - m);
                if (bn + wn + j * 16 + l15 == tgt) rtl[bm + rowl] = v;
            }
            l += __shfl_xor(l, 1);
            l += __shfl_xor(l, 2);
            l += __shfl_xor(l, 4);
            l += __shfl_xor(l, 8);
            if (l15 == 0) { Ms[rowl][w >> 1] = m; Ls[rowl][w >> 1] = l; }
        }
    }
    __syncthreads();
    if (tid < 128) {
        float m0 = Ms[tid][0], m1 = Ms[tid][1];
        float l0 = Ls[tid][0], l1 = Ls[tid][1];
        float m = fmaxf(m0, m1);
        float l = l0 * __expf(m0 - m) + l1 * __expf(m1 - m);
        part[(size_t)(bm + tid) * NT_ + blockIdx.x] = make_float2(m, l);
    }
}

// per-row log-sum-exp combine of NT_ partials -> nll
__global__ __launch_bounds__(256) void loss_row_kernel(const float2* __restrict__ part,
                                                       const float* __restrict__ rtl,
                                                       float* __restrict__ rnll) {
    int row = blockIdx.x;
    int tid = threadIdx.x;
    float m = -1e30f, l = 0.f;
    if (tid < NT_) { float2 p = part[(size_t)row * NT_ + tid]; m = p.x; l = p.y; }
    #pragma unroll
    for (int o = 1; o < 64; o <<= 1) {
        float mo = __shfl_xor(m, o), lo = __shfl_xor(l, o);
        float nm = fmaxf(m, mo);
        l = l * __expf(m - nm) + lo * __expf(mo - nm);
        m = nm;
    }
    __shared__ float sm[4], sl[4];
    int lane = tid & 63, wid = tid >> 6;
    if (lane == 0) { sm[wid] = m; sl[wid] = l; }
    __syncthreads();
    if (tid == 0) {
        float M = sm[0], L = sl[0];
        #pragma unroll
        for (int i = 1; i < 4; i++) {
            float nm = fmaxf(M, sm[i]);
            L = L * __expf(M - nm) + sl[i] * __expf(sm[i] - nm);
            M = nm;
        }
        int spos = row % S_;
        rnll[row] = (spos < S_ - 1) ? (M + logf(L)) - rtl[row] : 0.f;
    }
}

__global__ __launch_bounds__(256) void loss_sum_kernel(const float* __restrict__ rnll,
                                                       float* __restrict__ out) {
    __shared__ float sred[4];
    float s = 0.f;
    for (int row = threadIdx.x; row < BS_; row += 256) s += rnll[row];
    for (int o = 32; o > 0; o >>= 1) s += __shfl_down(s, o);
    int lane = threadIdx.x & 63, wid = threadIdx.x >> 6;
    if (lane == 0) sred[wid] = s;
    __syncthreads();
    if (threadIdx.x == 0)
        out[0] = (sred[0] + sred[1] + sred[2] + sred[3]) * (1.0f / (B_ * (S_ - 1)));
}

// ---------------- flash attention (MFMA) ----------------
#define UNPACK8(u, dst) { (dst)[0]=blo((u).x);(dst)[1]=bhi((u).x);(dst)[2]=blo((u).y);(dst)[3]=bhi((u).y);(dst)[4]=blo((u).z);(dst)[5]=bhi((u).z);(dst)[6]=blo((u).w);(dst)[7]=bhi((u).w); }

__global__ __launch_bounds__(256) void attn_kernel(const unsigned short* __restrict__ qkv,
                                                   unsigned short* __restrict__ attno) {
    int qt = blockIdx.x, h = blockIdx.y, b = blockIdx.z;
    int tid = threadIdx.x;
    int w = tid >> 6, lane = tid & 63;
    int l15 = lane & 15, quad = lane >> 4;

    __shared__ unsigned short Ks[64][72];
    __shared__ float Vt[64][68];
    __shared__ unsigned short Ps[4][16][72];

    short8 aq[2];
    {
        const unsigned short* gq = qkv + (size_t)(b * S_ + qt * 64 + w * 16 + l15) * D3_ + h * HD_ + quad * 8;
        aq[0] = *(const short8*)(gq);
        aq[1] = *(const short8*)(gq + 32);
    }

    f32x4 oacc[4] = {};
    float m_i[4] = {-1e30f, -1e30f, -1e30f, -1e30f};
    float l_i[4] = {0.f, 0.f, 0.f, 0.f};

    int krr = tid >> 3, kseg = tid & 7;
    int vrr = tid >> 2, vd0 = (tid & 3) * 16;

    for (int kt = 0; kt <= qt; kt++) {
        __syncthreads();
        {
            const unsigned short* gk = qkv + (size_t)(b * S_ + kt * 64 + krr) * D3_ + D_ + h * HD_ + kseg * 8;
            uint4 u0 = *(const uint4*)gk;
            uint4 u1 = *(const uint4*)(gk + (size_t)32 * D3_);
            *(uint4*)&Ks[krr][kseg * 8] = u0;
            *(uint4*)&Ks[krr + 32][kseg * 8] = u1;
        }
        {
            const unsigned short* gv = qkv + (size_t)(b * S_ + kt * 64 + vrr) * D3_ + 2 * D_ + h * HD_ + vd0;
            uint4 v0 = *(const uint4*)gv;
            uint4 v1 = *(const uint4*)(gv + 8);
            float tmp[16];
            UNPACK8(v0, tmp); UNPACK8(v1, tmp + 8);
            #pragma unroll
            for (int u = 0; u < 16; u++) Vt[vd0 + u][vrr] = tmp[u];
        }
        __syncthreads();

        f32x4 sc[4] = {};
        #pragma unroll
        for (int kk = 0; kk < 2; kk++)
            #pragma unroll
            for (int j = 0; j < 4; j++) {
                short8 bk = *(const short8*)&Ks[j * 16 + l15][kk * 32 + quad * 8];
                sc[j] = __builtin_amdgcn_mfma_f32_16x16x32_bf16(aq[kk], bk, sc[j], 0, 0, 0);
            }

        bool diag = (kt == qt);
        #pragma unroll
        for (int j = 0; j < 4; j++)
            #pragma unroll
            for (int r = 0; r < 4; r++) {
                float v = sc[j][r] * 0.125f;
                if (diag && (j * 16 + l15) > (w * 16 + quad * 4 + r)) v = -1e30f;
                sc[j][r] = v;
            }

        #pragma unroll
        for (int r = 0; r < 4; r++) {
            float rm = fmaxf(fmaxf(sc[0][r], sc[1][r]), fmaxf(sc[2][r], sc[3][r]));
            rm = fmaxf(rm, __shfl_xor(rm, 1));
            rm = fmaxf(rm, __shfl_xor(rm, 2));
            rm = fmaxf(rm, __shfl_xor(rm, 4));
            rm = fmaxf(rm, __shfl_xor(rm, 8));
            float mnew = fmaxf(m_i[r], rm);
            float alpha = __expf(m_i[r] - mnew);
            float p0 = __expf(sc[0][r] - mnew);
            float p1 = __expf(sc[1][r] - mnew);
            float p2 = __expf(sc[2][r] - mnew);
            float p3 = __expf(sc[3][r] - mnew);
            float ls = p0 + p1 + p2 + p3;
            ls += __shfl_xor(ls, 1);
            ls += __shfl_xor(ls, 2);
            ls += __shfl_xor(ls, 4);
            ls += __shfl_xor(ls, 8);
            l_i[r] = l_i[r] * alpha + ls;
            m_i[r] = mnew;
            oacc[0][r] *= alpha; oacc[1][r] *= alpha;
            oacc[2][r] *= alpha; oacc[3][r] *= alpha;
            Ps[w][quad * 4 + r][ 0 + l15] = f2b(p0);
            Ps[w][quad * 4 + r][16 + l15] = f2b(p1);
            Ps[w][quad * 4 + r][32 + l15] = f2b(p2);
            Ps[w][quad * 4 + r][48 + l15] = f2b(p3);
        }

        #pragma unroll
        for (int kk = 0; kk < 2; kk++) {
            short8 pa = *(const short8*)&Ps[w][l15][kk * 32 + quad * 8];
            #pragma unroll
            for (int j = 0; j < 4; j++) {
                const float* vp = &Vt[j * 16 + l15][kk * 32 + quad * 8];
                f32x4 f0 = *(const f32x4*)vp;
                f32x4 f1 = *(const f32x4*)(vp + 4);
                unsigned int b0 = (__float_as_uint(f0[1]) & 0xffff0000u) | (__float_as_uint(f0[0]) >> 16);
                unsigned int b1 = (__float_as_uint(f0[3]) & 0xffff0000u) | (__float_as_uint(f0[2]) >> 16);
                unsigned int b2 = (__float_as_uint(f1[1]) & 0xffff0000u) | (__float_as_uint(f1[0]) >> 16);
                unsigned int b3 = (__float_as_uint(f1[3]) & 0xffff0000u) | (__float_as_uint(f1[2]) >> 16);
                union { uint4v u; short8 s; } cvt;
                cvt.u = (uint4v){b0, b1, b2, b3};
                oacc[j] = __builtin_amdgcn_mfma_f32_16x16x32_bf16(pa, cvt.s, oacc[j], 0, 0, 0);
            }
        }
    }

    #pragma unroll
    for (int r = 0; r < 4; r++) {
        float inv = 1.0f / l_i[r];
        size_t row = (size_t)(b * S_ + qt * 64 + w * 16 + quad * 4 + r);
        #pragma unroll
        for (int j = 0; j < 4; j++)
            attno[row * D_ + h * HD_ + j * 16 + l15] = f2b(oacc[j][r] * inv);
    }
}

// ---------------- launch ----------------

extern "C" void kernel_launch(void* const* d_in, const int* in_sizes, int n_in,
                              void* d_out, int out_size, void* d_ws, size_t ws_size,
                              hipStream_t stream) {
    const int*   ids    = (const int*)d_in[0];
    const int*   labels = (const int*)d_in[1];
    const float* lam    = (const float*)d_in[2];
    const float* emb    = (const float*)d_in[3];
    const float* Wqkv   = (const float*)d_in[4];
    const float* Wo     = (const float*)d_in[5];
    const float* W1     = (const float*)d_in[6];
    const float* W2     = (const float*)d_in[7];
    const float* g1     = (const float*)d_in[8];
    const float* g2     = (const float*)d_in[9];
    const float* gf     = (const float*)d_in[10];
    const float* dEmb   = (const float*)d_in[11];
    const float* dWqkv  = (const float*)d_in[12];
    const float* dWo    = (const float*)d_in[13];
    const float* dW1    = (const float*)d_in[14];
    const float* dW2    = (const float*)d_in[15];
    const float* dG1    = (const float*)d_in[16];
    const float* dG2    = (const float*)d_in[17];
    const float* dGf    = (const float*)d_in[18];
    float* out = (float*)d_out;

    char* wsb = (char*)d_ws;
    size_t off = 0;
    auto alloc = [&](size_t bytes) {
        off = (off + 255) & ~(size_t)255;
        void* p = wsb + off;
        off += bytes;
        return p;
    };
    unsigned short* embm  = (unsigned short*)alloc((size_t)V_ * D_ * 2);
    unsigned short* WqkvT = (unsigned short*)alloc((size_t)L_ * D3_ * D_ * 2);
    unsigned short* WoT   = (unsigned short*)alloc((size_t)L_ * D_ * D_ * 2);
    unsigned short* W1T   = (unsigned short*)alloc((size_t)L_ * DFF_ * D_ * 2);
    unsigned short* W2T   = (unsigned short*)alloc((size_t)L_ * D_ * DFF_ * 2);
    float* g1m = (float*)alloc((size_t)L_ * D_ * 4);
    float* g2m = (float*)alloc((size_t)L_ * D_ * 4);
    float* gfm = (float*)alloc((size_t)D_ * 4);
    float* h   = (float*)alloc((size_t)BS_ * D_ * 4);
    unsigned short* a_bf  = (unsigned short*)alloc((size_t)BS_ * D_ * 2);
    unsigned short* qkv   = (unsigned short*)alloc((size_t)BS_ * D3_ * 2);
    unsigned short* attno = (unsigned short*)alloc((size_t)BS_ * D_ * 2);
    unsigned short* ffh   = (unsigned short*)alloc((size_t)BS_ * DFF_ * 2);
    float2* part = (float2*)alloc((size_t)BS_ * NT_ * 8);
    float* rtl  = (float*)alloc(BS_ * 4);
    float* rnll = (float*)alloc(BS_ * 4);

    // ---- merges ----
    merge_bf16_kernel<<<4096, 256, 0, stream>>>(emb, dEmb, (size_t)V_ * D_, lam, embm, (size_t)V_ * D_ / 4);
    for (int l = 0; l < L_; l++) {
        mt_kernel<<<dim3(D3_ / 64, D_ / 64), 256, 0, stream>>>(
            Wqkv + (size_t)l * D_ * D3_, dWqkv + (size_t)l * D_ * D3_, (size_t)L_ * D_ * D3_,
            lam, WqkvT + (size_t)l * D3_ * D_, D_, D3_);
        mt_kernel<<<dim3(D_ / 64, D_ / 64), 256, 0, stream>>>(
            Wo + (size_t)l * D_ * D_, dWo + (size_t)l * D_ * D_, (size_t)L_ * D_ * D_,
            lam, WoT + (size_t)l * D_ * D_, D_, D_);
        mt_kernel<<<dim3(DFF_ / 64, D_ / 64), 256, 0, stream>>>(
            W1 + (size_t)l * D_ * DFF_, dW1 + (size_t)l * D_ * DFF_, (size_t)L_ * D_ * DFF_,
            lam, W1T + (size_t)l * DFF_ * D_, D_, DFF_);
        mt_kernel<<<dim3(D_ / 64, DFF_ / 64), 256, 0, stream>>>(
            W2 + (size_t)l * DFF_ * D_, dW2 + (size_t)l * DFF_ * D_, (size_t)L_ * DFF_ * D_,
            lam, W2T + (size_t)l * D_ * DFF_, DFF_, D_);
    }
    merge_f32_kernel<<<8, 256, 0, stream>>>(g1, dG1, (size_t)L_ * D_, lam, g1m, L_ * D_);
    merge_f32_kernel<<<8, 256, 0, stream>>>(g2, dG2, (size_t)L_ * D_, lam, g2m, L_ * D_);
    merge_f32_kernel<<<4, 256, 0, stream>>>(gf, dGf, (size_t)D_, lam, gfm, D_);

    // ---- embedding ----
    embed_kernel<<<BS_, 256, 0, stream>>>(ids, embm, h);

    // ---- layers ----
    for (int l = 0; l < L_; l++) {
        ln_kernel<<<BS_, 256, 0, stream>>>(h, g1m + l * D_, a_bf);
        gemm_mfma<2><<<dim3(D3_ / 128, BS_ / 128), 256, 0, stream>>>(
            a_bf, WqkvT + (size_t)l * D3_ * D_, nullptr, qkv, BS_, D3_, D_);
        attn_kernel<<<dim3(S_ / 64, H_, B_), 256, 0, stream>>>(qkv, attno);
        gemm_mfma<1><<<dim3(D_ / 128, BS_ / 128), 256, 0, stream>>>(
            attno, WoT + (size_t)l * D_ * D_, h, nullptr, BS_, D_, D_);
        ln_kernel<<<BS_, 256, 0, stream>>>(h, g2m + l * D_, a_bf);
        gemm_mfma<3><<<dim3(DFF_ / 128, BS_ / 128), 256, 0, stream>>>(
            a_bf, W1T + (size_t)l * DFF_ * D_, nullptr, ffh, BS_, DFF_, D_);
        gemm_mfma<1><<<dim3(D_ / 128, BS_ / 128), 256, 0, stream>>>(
            ffh, W2T + (size_t)l * D_ * DFF_, h, nullptr, BS_, D_, DFF_);
    }

    // ---- final LN ----
    ln_kernel<<<BS_, 256, 0, stream>>>(h, gfm, a_bf);

    // ---- fused logits + loss ----
    gemm_loss_kernel<<<dim3(NT_, BS_ / 128), 256, 0, stream>>>(a_bf, embm, labels, part, rtl);
    loss_row_kernel<<<BS_, 256, 0, stream>>>(part, rtl, rnll);
    loss_sum_kernel<<<1, 256, 0, stream>>>(rnll, out);
}